// Round 1
// baseline (820.696 us; speedup 1.0000x reference)
//
#include <hip/hip_runtime.h>

#define CC   256
#define GCH  32
#define GG   8
#define HH   56
#define WWID 56
#define KIN1 1608
#define NO1  72
#define NO2  288
#define PP   8          // positions per block
#define NCOL (PP + 2)   // staged cols = 10
#define FPAD 1616       // feat row stride (bf16 elems), padded for LDS banking
#define H2   112
#define W2D  112

__device__ __forceinline__ unsigned short f2b(float x) {
  unsigned int u = __float_as_uint(x);
  u = (u + 0x7FFFu + ((u >> 16) & 1u)) >> 16;   // RNE fp32->bf16
  return (unsigned short)u;
}
__device__ __forceinline__ float b2f(unsigned short h) {
  return __uint_as_float(((unsigned int)h) << 16);
}

__global__ __launch_bounds__(256, 2)
void revo_fused(const float* __restrict__ in, const float* __restrict__ W1,
                const float* __restrict__ b1, const float* __restrict__ W2,
                const float* __restrict__ b2, float* __restrict__ out) {
  __shared__ float in_lds[CC * 3 * NCOL];                 // 30720 B
  __shared__ __align__(16) float u_lds[PP * FPAD / 2];    // 25856 B: feat(bf16) then y2(fp32, 9216B)
  __shared__ float y1_lds[PP * NO1];                      // 2304 B
  __shared__ float vmax_lds[GG * 3 * NCOL];               // 960 B
  unsigned short* feat = (unsigned short*)u_lds;

  const int t  = threadIdx.x;
  const int j0 = blockIdx.x * PP;
  const int i  = blockIdx.y;
  const int b  = blockIdx.z;
  const float* inb = in + (size_t)b * CC * HH * WWID;

  // ---- stage zero-padded input window: 256 ch x rows(i-1..i+1) x cols(j0-1..j0+8) ----
  for (int e = t; e < CC * 3 * NCOL; e += 256) {
    int c   = e / (3 * NCOL);
    int rem = e - c * (3 * NCOL);
    int r   = rem / NCOL;
    int jj  = rem - r * NCOL;
    int row = i - 1 + r;
    int col = j0 - 1 + jj;
    float v = 0.f;
    if (row >= 0 && row < HH && col >= 0 && col < WWID)
      v = inb[(c * HH + row) * WWID + col];
    in_lds[e] = v;
  }
  __syncthreads();

  // ---- phase A: feat = [x1(72) | x2(768) | x3(768)] per position, bf16 in LDS ----
  {
    const int c  = t;
    const int gc = c & (GCH - 1);
    float v[3 * NCOL];
#pragma unroll
    for (int e = 0; e < 3 * NCOL; ++e) v[e] = in_lds[c * (3 * NCOL) + e];

    // x2[c,kj] = max over ki  -> column max
    float colmax[NCOL];
#pragma unroll
    for (int jj = 0; jj < NCOL; ++jj)
      colmax[jj] = fmaxf(fmaxf(v[jj], v[NCOL + jj]), v[2 * NCOL + jj]);
#pragma unroll
    for (int p = 0; p < PP; ++p) {
#pragma unroll
      for (int kj = 0; kj < 3; ++kj)
        feat[p * FPAD + NO1 + c * 3 + kj] = f2b(colmax[p + kj]);
    }
    // x3[c,ki] = max over kj -> sliding row max
#pragma unroll
    for (int p = 0; p < PP; ++p) {
#pragma unroll
      for (int ki = 0; ki < 3; ++ki)
        feat[p * FPAD + NO1 + CC * 3 + c * 3 + ki] =
            f2b(fmaxf(fmaxf(v[ki * NCOL + p], v[ki * NCOL + p + 1]),
                      v[ki * NCOL + p + 2]));
    }
    // x1[g,ki,kj] = max over 32 channels: reduce raw window across lanes first
#pragma unroll
    for (int e = 0; e < 3 * NCOL; ++e) {
      float m = v[e];
      m = fmaxf(m, __shfl_xor(m, 1));
      m = fmaxf(m, __shfl_xor(m, 2));
      m = fmaxf(m, __shfl_xor(m, 4));
      m = fmaxf(m, __shfl_xor(m, 8));
      m = fmaxf(m, __shfl_xor(m, 16));
      if (gc == 0) vmax_lds[(c >> 5) * (3 * NCOL) + e] = m;
    }
  }
  __syncthreads();
  for (int e = t; e < GG * PP * 9; e += 256) {   // 576 items
    int g   = e / (PP * 9);
    int rem = e - g * (PP * 9);
    int p   = rem / 9;
    int r9  = rem - p * 9;
    int ki  = r9 / 3;
    int kj  = r9 - ki * 3;
    feat[p * FPAD + g * 9 + r9] = f2b(vmax_lds[g * (3 * NCOL) + ki * NCOL + p + kj]);
  }
  __syncthreads();

  // ---- phase B: y1 = W1 * feat + b1 (72 x 8) ----
  const int o_l = t >> 3;      // 0..31
  const int p   = t & 7;       // 0..7
  {
    const unsigned short* frow = feat + p * FPAD;
    const float* wr0 = W1 + (size_t)o_l * KIN1;
    const float* wr1 = W1 + (size_t)(o_l + 32) * KIN1;
    float a0 = 0.f, a1 = 0.f, a2 = 0.f;
    if (o_l < 8) {                                   // wave-uniform (wave 0 only)
      const float* wr2 = W1 + (size_t)(o_l + 64) * KIN1;
      for (int k = 0; k < KIN1; k += 4) {
        ushort4 u4 = *(const ushort4*)(frow + k);
        float f0 = b2f(u4.x), f1 = b2f(u4.y), f2v = b2f(u4.z), f3 = b2f(u4.w);
        float4 wa = *(const float4*)(wr0 + k);
        a0 = fmaf(wa.x, f0, a0); a0 = fmaf(wa.y, f1, a0);
        a0 = fmaf(wa.z, f2v, a0); a0 = fmaf(wa.w, f3, a0);
        float4 wb = *(const float4*)(wr1 + k);
        a1 = fmaf(wb.x, f0, a1); a1 = fmaf(wb.y, f1, a1);
        a1 = fmaf(wb.z, f2v, a1); a1 = fmaf(wb.w, f3, a1);
        float4 wc = *(const float4*)(wr2 + k);
        a2 = fmaf(wc.x, f0, a2); a2 = fmaf(wc.y, f1, a2);
        a2 = fmaf(wc.z, f2v, a2); a2 = fmaf(wc.w, f3, a2);
      }
      y1_lds[p * NO1 + o_l + 64] = a2 + b1[o_l + 64];
    } else {
      for (int k = 0; k < KIN1; k += 4) {
        ushort4 u4 = *(const ushort4*)(frow + k);
        float f0 = b2f(u4.x), f1 = b2f(u4.y), f2v = b2f(u4.z), f3 = b2f(u4.w);
        float4 wa = *(const float4*)(wr0 + k);
        a0 = fmaf(wa.x, f0, a0); a0 = fmaf(wa.y, f1, a0);
        a0 = fmaf(wa.z, f2v, a0); a0 = fmaf(wa.w, f3, a0);
        float4 wb = *(const float4*)(wr1 + k);
        a1 = fmaf(wb.x, f0, a1); a1 = fmaf(wb.y, f1, a1);
        a1 = fmaf(wb.z, f2v, a1); a1 = fmaf(wb.w, f3, a1);
      }
    }
    y1_lds[p * NO1 + o_l]      = a0 + b1[o_l];
    y1_lds[p * NO1 + o_l + 32] = a1 + b1[o_l + 32];
  }
  __syncthreads();   // feat dead beyond this point; u_lds reused as y2

  // ---- phase C: y2 = W2 * y1 + b2 (288 x 8), into u_lds (fp32) ----
  float* y2 = u_lds;
  {
    const float* yrow = y1_lds + p * NO1;
#pragma unroll 1
    for (int pass = 0; pass < 9; ++pass) {
      int o = pass * 32 + o_l;
      const float* wrow = W2 + o * NO1;
      float a = b2[o];
#pragma unroll
      for (int kk = 0; kk < NO1; kk += 4) {
        float4 w4 = *(const float4*)(wrow + kk);
        float4 y4 = *(const float4*)(yrow + kk);
        a = fmaf(w4.x, y4.x, a); a = fmaf(w4.y, y4.y, a);
        a = fmaf(w4.z, y4.z, a); a = fmaf(w4.w, y4.w, a);
      }
      y2[o * PP + p] = a;
    }
  }
  __syncthreads();

  // ---- phase D: softmax over k (9) for each (g, n, p) — 256 slots, in place ----
  {
    const int g  = t >> 5;
    const int n  = (t >> 3) & 3;
    const int ps = t & 7;
    float v9[9];
    float m = -1e30f;
#pragma unroll
    for (int k = 0; k < 9; ++k) {
      v9[k] = y2[(g * 36 + k * 4 + n) * PP + ps];
      m = fmaxf(m, v9[k]);
    }
    float s = 0.f;
#pragma unroll
    for (int k = 0; k < 9; ++k) { v9[k] = __expf(v9[k] - m); s += v9[k]; }
    float inv = 1.f / s;
#pragma unroll
    for (int k = 0; k < 9; ++k) y2[(g * 36 + k * 4 + n) * PP + ps] = v9[k] * inv;
  }
  __syncthreads();

  // ---- phase E: agg + store. lane=(c_lo,p): 4 outputs (n0,n1) per (c,p) ----
  {
    const int w    = t >> 6;
    const int lane = t & 63;
    const int c_lo = lane >> 3;
    const int pe   = lane & 7;
    for (int cc = w; cc < 32; cc += 4) {
      const int c = cc * 8 + c_lo;
      const int g = c >> 5;
      float xv[9];
#pragma unroll
      for (int ki = 0; ki < 3; ++ki)
#pragma unroll
        for (int kj = 0; kj < 3; ++kj)
          xv[ki * 3 + kj] = in_lds[c * (3 * NCOL) + ki * NCOL + pe + kj];
      float a0 = 0.f, a1 = 0.f, a2 = 0.f, a3 = 0.f;
#pragma unroll
      for (int k = 0; k < 9; ++k) {
        const float xk = xv[k];
        const float* wg = &y2[(g * 36 + k * 4) * PP + pe];
        a0 = fmaf(xk, wg[0 * PP], a0);
        a1 = fmaf(xk, wg[1 * PP], a1);
        a2 = fmaf(xk, wg[2 * PP], a2);
        a3 = fmaf(xk, wg[3 * PP], a3);
      }
      const size_t obase =
          ((size_t)(b * CC + c) * H2 + (size_t)(2 * i)) * W2D + (size_t)(2 * (j0 + pe));
      out[obase]           = a0;   // n0=0,n1=0
      out[obase + 1]       = a1;   // n0=0,n1=1
      out[obase + W2D]     = a2;   // n0=1,n1=0
      out[obase + W2D + 1] = a3;   // n0=1,n1=1
    }
  }
}

extern "C" void kernel_launch(void* const* d_in, const int* in_sizes, int n_in,
                              void* d_out, int out_size, void* d_ws, size_t ws_size,
                              hipStream_t stream) {
  const float* in  = (const float*)d_in[0];
  const float* W1  = (const float*)d_in[1];
  const float* b1  = (const float*)d_in[2];
  const float* W2  = (const float*)d_in[3];
  const float* b2  = (const float*)d_in[4];
  float* out = (float*)d_out;
  const int B = in_sizes[0] / (CC * HH * WWID);
  dim3 grid(WWID / PP, HH, B);
  revo_fused<<<grid, 256, 0, stream>>>(in, W1, b1, W2, b2, out);
}

// Round 2
// 374.622 us; speedup vs baseline: 2.1907x; 2.1907x over previous
//
#include <hip/hip_runtime.h>

#define CC   256
#define HH   56
#define WWID 56
#define KIN1 1608
#define KP1  1632          // conv1 K padded to 51*32
#define KPS  1640          // feat LDS row stride (bank-friendly, 16B-aligned rows)
#define NO1  72
#define NO2  288
#define PPB  14            // positions per block
#define NCOLS 16           // staged cols = PPB+2
#define H2   112
#define W2D  112

typedef unsigned short u16;
typedef unsigned int   u32;
typedef __attribute__((ext_vector_type(8))) short v8s;
typedef __attribute__((ext_vector_type(4))) float v4f;

#define W1BF_ELEMS (80 * KP1)            // 130560
#define W2BF_OFF_B 262144                // byte offset of W2bf in ws
#define Y1_OFF_B   524288                // byte offset of y1 in ws

__device__ __forceinline__ u16 f2b(float x) {
  u32 u = __float_as_uint(x);
  u = (u + 0x7FFFu + ((u >> 16) & 1u)) >> 16;   // RNE fp32->bf16
  return (u16)u;
}
__device__ __forceinline__ float b2f(u16 h) {
  return __uint_as_float(((u32)h) << 16);
}

// ---------------- weight conversion: W1 -> bf16 [80][1632], W2 -> bf16 [288][96]
__global__ void kConvW(const float* __restrict__ W1, const float* __restrict__ W2,
                       u16* __restrict__ w1bf, u16* __restrict__ w2bf) {
  int idx = blockIdx.x * 256 + threadIdx.x;
  if (idx < W1BF_ELEMS) {
    int m = idx / KP1, k = idx - m * KP1;
    w1bf[idx] = (m < NO1 && k < KIN1) ? f2b(W1[m * KIN1 + k]) : (u16)0;
  } else {
    int i2 = idx - W1BF_ELEMS;
    if (i2 < NO2 * 96) {
      int m = i2 / 96, k = i2 - m * 96;
      w2bf[i2] = (k < NO1) ? f2b(W2[m * NO1 + k]) : (u16)0;
    }
  }
}

// ---------------- kernel A: feat build + conv1 MFMA -> y1 (72 x 14 per block)
__global__ __launch_bounds__(256, 2)
void kA(const float* __restrict__ in, const u16* __restrict__ w1bf,
        const float* __restrict__ b1, float* __restrict__ y1ws) {
  __shared__ u16   feat[16 * KPS];     // 52480 B ; also aliased as fp32 partials later
  __shared__ float win[64 * 49];       // 12544 B
  __shared__ float gmax_s[96];         // 384 B      total 65408 B

  const int t  = threadIdx.x;
  const int jt = blockIdx.x, i = blockIdx.y, b = blockIdx.z;
  const int j0 = jt * PPB;
  const float* inb = in + (size_t)b * CC * HH * WWID;

  // zero feat pad k in [1608,1640) for all 16 n-rows (512 u16 = 256 u32, 1/thread)
  {
    int n = t >> 4, off = t & 15;
    *(u32*)&feat[n * KPS + KIN1 + off * 2] = 0u;
  }

  // ---- feat build: 4 passes of 64 channels ----
  for (int q = 0; q < 4; ++q) {
    for (int e = t; e < 64 * 48; e += 256) {
      int c_l = e / 48, rem = e - c_l * 48, r = rem >> 4, col = rem & 15;
      int row = i - 1 + r, colg = j0 - 1 + col;
      float v = 0.f;
      if (row >= 0 && row < HH && colg >= 0 && colg < WWID)
        v = inb[((q * 64 + c_l) * HH + row) * WWID + colg];
      win[c_l * 49 + r * 16 + col] = v;
    }
    __syncthreads();
    // x2 (col-max over ki) and x3 (row-max over kj)
    {
      const int c_l = t >> 2, sub = t & 3;
      const int cg = q * 64 + c_l;
      const int n0 = sub * 4, cnt = (sub == 3) ? 2 : 4;
      float w3[3][6], cm[6];
#pragma unroll
      for (int r = 0; r < 3; ++r)
        for (int jx = 0; jx < cnt + 2; ++jx)
          w3[r][jx] = win[c_l * 49 + r * 16 + n0 + jx];
      for (int jx = 0; jx < cnt + 2; ++jx)
        cm[jx] = fmaxf(fmaxf(w3[0][jx], w3[1][jx]), w3[2][jx]);
      for (int jn = 0; jn < cnt; ++jn) {
        const int n = n0 + jn;
        u16* fr = &feat[n * KPS];
#pragma unroll
        for (int kj = 0; kj < 3; ++kj) fr[NO1 + cg * 3 + kj] = f2b(cm[jn + kj]);
#pragma unroll
        for (int r = 0; r < 3; ++r)
          fr[NO1 + 768 + cg * 3 + r] =
              f2b(fmaxf(fmaxf(w3[r][jn], w3[r][jn + 1]), w3[r][jn + 2]));
      }
    }
    // x1 stage A: group-max over 32 channels of the raw window
    if (t < 96) {
      int g2 = t / 48, rc = t - g2 * 48;
      float m = -1e30f;
      for (int ci = 0; ci < 32; ++ci)
        m = fmaxf(m, win[(g2 * 32 + ci) * 49 + rc]);
      gmax_s[t] = m;
    }
    __syncthreads();
    // x1 stage B: scatter to feat rows [0,72)
    if (t < 252) {
      int g2 = t / 126, rem = t - g2 * 126, r9 = rem / 14, n = rem - r9 * 14;
      int ki = r9 / 3, kj = r9 - ki * 3;
      feat[n * KPS + (q * 2 + g2) * 9 + r9] = f2b(gmax_s[g2 * 48 + ki * 16 + n + kj]);
    }
    __syncthreads();
  }

  // ---- conv1 MFMA: y1[80pad x 16pad] = W1bf[80][1632] * feat^T, waves split K ----
  const int w = t >> 6, lane = t & 63;
  const int ml = lane & 15, quad = lane >> 4;
  v4f acc[5];
#pragma unroll
  for (int mt = 0; mt < 5; ++mt) acc[mt] = (v4f){0.f, 0.f, 0.f, 0.f};
  const int ks0 = w * 13, ks1 = (w == 3) ? 51 : ks0 + 13;
  for (int ks = ks0; ks < ks1; ++ks) {
    const int k0 = ks * 32 + quad * 8;
    v8s bf = *(v8s*)&feat[ml * KPS + k0];               // B[k][n], n=lane&15
#pragma unroll
    for (int mt = 0; mt < 5; ++mt) {
      v8s af = *(const v8s*)&w1bf[(mt * 16 + ml) * KP1 + k0];  // A[m][k], m=lane&15
      acc[mt] = __builtin_amdgcn_mfma_f32_16x16x32_bf16(af, bf, acc[mt], 0, 0, 0);
    }
  }
  __syncthreads();
  float* part = (float*)feat;   // [4w][5mt][16col][16row] = 20480 B
#pragma unroll
  for (int mt = 0; mt < 5; ++mt)
    *(v4f*)&part[((w * 5 + mt) * 16 + ml) * 16 + quad * 4] = acc[mt];
  __syncthreads();
  const int bid = (b * HH + i) * 4 + jt;
  for (int e = t; e < NO1 * PPB; e += 256) {
    int m = e / PPB, n = e - m * PPB;
    float s = 0.f;
#pragma unroll
    for (int ww = 0; ww < 4; ++ww)
      s += part[((ww * 5 + (m >> 4)) * 16 + n) * 16 + (m & 15)];
    y1ws[(size_t)bid * (NO1 * PPB) + e] = s + b1[m];
  }
}

// ---------------- kernel B: conv2 MFMA + softmax + aggregation + fold-store
__global__ __launch_bounds__(256, 2)
void kB(const float* __restrict__ in, const u16* __restrict__ w2bf,
        const float* __restrict__ b2, const float* __restrict__ y1ws,
        float* __restrict__ out) {
  __shared__ u16   win[CC * 50];       // 25600 B (bf16 window)
  __shared__ u16   y1b[16 * 104];      // 3328 B  (bf16 y1, [n][k] padded to 96)
  __shared__ float y2L[16 * 296];      // 18944 B ([n][o]) total 47872 B

  const int t  = threadIdx.x;
  const int jt = blockIdx.x, i = blockIdx.y, b = blockIdx.z;
  const int j0 = jt * PPB;
  const int bid = (b * HH + i) * 4 + jt;
  const float* inb = in + (size_t)b * CC * HH * WWID;

  // stage window (bf16) — zero-padded borders participate in nothing here (agg only)
  for (int e = t; e < CC * 48; e += 256) {
    int c = e / 48, rem = e - c * 48, r = rem >> 4, col = rem & 15;
    int row = i - 1 + r, colg = j0 - 1 + col;
    float v = 0.f;
    if (row >= 0 && row < HH && colg >= 0 && colg < WWID)
      v = inb[(c * HH + row) * WWID + colg];
    win[c * 50 + r * 16 + col] = f2b(v);
  }
  // y1 tile: load fp32 [m][n] from ws, transpose to bf16 [n][m]
  for (int e = t; e < NO1 * PPB; e += 256) {
    int m = e / PPB, n = e - m * PPB;
    y1b[n * 104 + m] = f2b(y1ws[(size_t)bid * (NO1 * PPB) + e]);
  }
  {  // zero-pad y1b k in [72,104)
    int n = t >> 4, off = t & 15;
    *(u32*)&y1b[n * 104 + NO1 + off * 2] = 0u;
  }
  __syncthreads();

  // conv2 MFMA: y2[288 x 14] = W2bf[288][96] * y1b^T ; waves split M-tiles {5,5,4,4}
  const int w = t >> 6, lane = t & 63;
  const int nl = lane & 15, quad = lane >> 4;
  {
    v8s bfr[3];
#pragma unroll
    for (int ks = 0; ks < 3; ++ks)
      bfr[ks] = *(v8s*)&y1b[nl * 104 + ks * 32 + quad * 8];
    const int mt0 = (w < 2) ? 5 * w : 10 + 4 * (w - 2);
    const int mtn = (w < 2) ? 5 : 4;
    for (int mi = 0; mi < mtn; ++mi) {
      const int mt = mt0 + mi;
      v4f acc = (v4f){0.f, 0.f, 0.f, 0.f};
#pragma unroll
      for (int ks = 0; ks < 3; ++ks) {
        v8s af = *(const v8s*)&w2bf[(mt * 16 + nl) * 96 + ks * 32 + quad * 8];
        acc = __builtin_amdgcn_mfma_f32_16x16x32_bf16(af, bfr[ks], acc, 0, 0, 0);
      }
      const int o0 = mt * 16 + quad * 4;
      const float4 bv = *(const float4*)(b2 + o0);
      acc[0] += bv.x; acc[1] += bv.y; acc[2] += bv.z; acc[3] += bv.w;
      *(v4f*)&y2L[nl * 296 + o0] = acc;
    }
  }
  __syncthreads();

  // softmax over k(9) for each (g, nn, n): 448 slots, in place
  for (int s = t; s < 448; s += 256) {
    int g = s / 56, rem = s - g * 56, nn = rem / PPB, n = rem - nn * PPB;
    float* bp = &y2L[n * 296 + g * 36 + nn];
    float v9[9], m = -1e30f;
#pragma unroll
    for (int k = 0; k < 9; ++k) { v9[k] = bp[k * 4]; m = fmaxf(m, v9[k]); }
    float sum = 0.f;
#pragma unroll
    for (int k = 0; k < 9; ++k) { v9[k] = __expf(v9[k] - m); sum += v9[k]; }
    float inv = 1.f / sum;
#pragma unroll
    for (int k = 0; k < 9; ++k) bp[k * 4] = v9[k] * inv;
  }
  __syncthreads();

  // aggregation: thread=(g, csub, n); 36 weights hoisted to regs, 16 channels each
  {
    const int g = lane >> 3, csub = w >> 1, n = (w & 1) * 8 + (lane & 7);
    if (n < PPB) {
      float wv[36];
#pragma unroll
      for (int kk = 0; kk < 36; ++kk) wv[kk] = y2L[n * 296 + g * 36 + kk];
      const size_t ob = ((size_t)(b * CC) * H2 + (size_t)(2 * i)) * W2D
                        + (size_t)(2 * (j0 + n));
      for (int ci = 0; ci < 16; ++ci) {
        const int c = g * 32 + csub * 16 + ci;
        const u16* wr = &win[c * 50];
        float a0 = 0.f, a1 = 0.f, a2 = 0.f, a3 = 0.f;
#pragma unroll
        for (int ki = 0; ki < 3; ++ki)
#pragma unroll
          for (int kj = 0; kj < 3; ++kj) {
            const float x = b2f(wr[ki * 16 + n + kj]);
            const int k4 = (ki * 3 + kj) * 4;
            a0 = fmaf(x, wv[k4], a0);
            a1 = fmaf(x, wv[k4 + 1], a1);
            a2 = fmaf(x, wv[k4 + 2], a2);
            a3 = fmaf(x, wv[k4 + 3], a3);
          }
        const size_t obc = ob + (size_t)c * H2 * W2D;
        float2 lo; lo.x = a0; lo.y = a1;
        float2 hi; hi.x = a2; hi.y = a3;
        *(float2*)&out[obc] = lo;
        *(float2*)&out[obc + W2D] = hi;
      }
    }
  }
}

extern "C" void kernel_launch(void* const* d_in, const int* in_sizes, int n_in,
                              void* d_out, int out_size, void* d_ws, size_t ws_size,
                              hipStream_t stream) {
  const float* in = (const float*)d_in[0];
  const float* W1 = (const float*)d_in[1];
  const float* b1 = (const float*)d_in[2];
  const float* W2 = (const float*)d_in[3];
  const float* b2 = (const float*)d_in[4];
  float* out = (float*)d_out;

  u16*   w1bf = (u16*)d_ws;
  u16*   w2bf = (u16*)((char*)d_ws + W2BF_OFF_B);
  float* y1ws = (float*)((char*)d_ws + Y1_OFF_B);

  const int B = in_sizes[0] / (CC * HH * WWID);

  kConvW<<<dim3((W1BF_ELEMS + NO2 * 96) / 256), 256, 0, stream>>>(W1, W2, w1bf, w2bf);
  dim3 grid(WWID / PPB, HH, B);
  kA<<<grid, 256, 0, stream>>>(in, w1bf, b1, y1ws);
  kB<<<grid, 256, 0, stream>>>(in, w2bf, b2, y1ws, out);
}

// Round 3
// 223.609 us; speedup vs baseline: 3.6702x; 1.6753x over previous
//
#include <hip/hip_runtime.h>

#define CC   256
#define HH   56
#define WWID 56
#define KIN1 1608
#define KP1  1632
#define NO1  72
#define NO2  288
#define PPB  14
#define H2   112
#define W2D  112

typedef unsigned short u16;
typedef unsigned int   u32;
typedef __attribute__((ext_vector_type(8))) short v8s;
typedef __attribute__((ext_vector_type(4))) float v4f;

#define W1BF_ELEMS (80 * KP1)
#define W2BF_OFF_B 262144

// LDS layout (bytes). Total 40192 -> 4 blocks/CU (4*40192 = 160768 <= 163840).
#define LDS_TOTAL 40192
#define OFF_A 0        // rowmaxT [16][776] u16 (24832) -> partials [4][5][16][16] f32 (20480) -> y2L [16][296] f32 (18944)
#define OFF_B 24832    // colmaxT [16][264] u16 (8448); later out-tile [64][60] f32 (15360) spans B..end
#define OFF_C 33280    // x1T / y1b [16][104] u16 (3328)
#define OFF_D 36608    // gmax_s [8][3][16] f32 (1536)

__device__ __forceinline__ u16 f2b(float x) {
  u32 u = __float_as_uint(x);
  u = (u + 0x7FFFu + ((u >> 16) & 1u)) >> 16;   // RNE fp32->bf16
  return (u16)u;
}

// ---- weight conversion; W1 columns PERMUTED to K-layout:
//   phys [0,768)    = x2 region: kj*256 + c      <- orig 72 + c*3 + kj
//   phys [768,1536) = x3 region: r*256 + c       <- orig 840 + c*3 + r
//   phys [1536,1632)= x1 region: m72 (<72), pad  <- orig m72
__global__ void kConvW(const float* __restrict__ W1, const float* __restrict__ W2,
                       u16* __restrict__ w1bf, u16* __restrict__ w2bf) {
  int idx = blockIdx.x * 256 + threadIdx.x;
  if (idx < W1BF_ELEMS) {
    int m = idx / KP1, k = idx - m * KP1;
    float v = 0.f;
    if (m < NO1) {
      int orig = -1;
      if (k < 768)                 orig = 72 + (k & 255) * 3 + (k >> 8);
      else if (k < 1536)           orig = 840 + (k & 255) * 3 + ((k - 768) >> 8);
      else if ((k - 1536) < NO1)   orig = k - 1536;
      if (orig >= 0) v = W1[m * KIN1 + orig];
    }
    w1bf[idx] = f2b(v);
  } else {
    int i2 = idx - W1BF_ELEMS;
    if (i2 < NO2 * 96) {
      int m = i2 / 96, k = i2 - m * 96;
      w2bf[i2] = (k < NO1) ? f2b(W2[m * NO1 + k]) : (u16)0;
    }
  }
}

__global__ __launch_bounds__(256, 4)
void kFused(const float* __restrict__ in, const u16* __restrict__ w1bf,
            const float* __restrict__ b1, const u16* __restrict__ w2bf,
            const float* __restrict__ b2, float* __restrict__ out) {
  __shared__ __align__(16) char lds[LDS_TOTAL];
  u16*   rowmaxT = (u16*)(lds + OFF_A);
  u16*   colmaxT = (u16*)(lds + OFF_B);
  u16*   x1T     = (u16*)(lds + OFF_C);   // later aliased as y1b
  float* gmax_s  = (float*)(lds + OFF_D);
  float* partA   = (float*)(lds + OFF_A); // partials, then y2L
  float* y2L     = (float*)(lds + OFF_A);
  float* tile    = (float*)(lds + OFF_B); // out transpose, [64][60] f32

  const int t  = threadIdx.x;
  const int jt = blockIdx.x, i = blockIdx.y, b = blockIdx.z;
  const int j0 = jt * PPB;
  const int c  = t;
  const int g  = c >> 5;
  const int gc = c & 31;
  const int w  = t >> 6, lane = t & 63;
  const int ml = lane & 15, quad = lane >> 4;

  // ---- zero x1T pads: cols[72,96) rows 0..15, and rows 14,15 cols[0,72). 264 u32.
  {
    u32* xu = (u32*)x1T;   // row stride 52 u32
    if (t < 132) {
#pragma unroll
      for (int rp2 = 0; rp2 < 2; ++rp2) {
        int idx = 2 * t + rp2;
        if (idx < 192) { int row = idx / 12; xu[row * 52 + 36 + (idx - row * 12)] = 0u; }
        else { int e = idx - 192; xu[(14 + e / 36) * 52 + (e % 36)] = 0u; }
      }
    }
  }

  // ---------------- P1: per-channel window load + maxes ----------------
  const float* rowbase0 = in + ((size_t)b * CC + c) * (HH * WWID);
  u32 win_p[3][8];
  float colmax[16];
#pragma unroll
  for (int k = 0; k < 16; ++k) colmax[k] = -3.0e38f;

#pragma unroll
  for (int r = 0; r < 3; ++r) {
    const int row = i - 1 + r;
    float sc[16];
    if (row < 0 || row >= HH) {
#pragma unroll
      for (int k = 0; k < 16; ++k) sc[k] = 0.f;
    } else {
      const float* rp = rowbase0 + row * WWID;
      float l[20];
      if (jt == 0) {
        const float4 a0 = *(const float4*)(rp), a1 = *(const float4*)(rp + 4),
                     a2 = *(const float4*)(rp + 8), a3 = *(const float4*)(rp + 12);
        l[0]=a0.x;l[1]=a0.y;l[2]=a0.z;l[3]=a0.w; l[4]=a1.x;l[5]=a1.y;l[6]=a1.z;l[7]=a1.w;
        l[8]=a2.x;l[9]=a2.y;l[10]=a2.z;l[11]=a2.w; l[12]=a3.x;l[13]=a3.y;l[14]=a3.z;l[15]=a3.w;
        sc[0] = 0.f;
#pragma unroll
        for (int k = 1; k < 16; ++k) sc[k] = l[k - 1];
      } else if (jt == 3) {
        const float* q = rp + 40;
        const float4 a0 = *(const float4*)(q), a1 = *(const float4*)(q + 4),
                     a2 = *(const float4*)(q + 8), a3 = *(const float4*)(q + 12);
        l[0]=a0.x;l[1]=a0.y;l[2]=a0.z;l[3]=a0.w; l[4]=a1.x;l[5]=a1.y;l[6]=a1.z;l[7]=a1.w;
        l[8]=a2.x;l[9]=a2.y;l[10]=a2.z;l[11]=a2.w; l[12]=a3.x;l[13]=a3.y;l[14]=a3.z;l[15]=a3.w;
#pragma unroll
        for (int k = 0; k < 15; ++k) sc[k] = l[k + 1];
        sc[15] = 0.f;
      } else {
        const float* q = rp + ((jt == 1) ? 12 : 24);
        const float4 a0 = *(const float4*)(q), a1 = *(const float4*)(q + 4),
                     a2 = *(const float4*)(q + 8), a3 = *(const float4*)(q + 12),
                     a4 = *(const float4*)(q + 16);
        l[0]=a0.x;l[1]=a0.y;l[2]=a0.z;l[3]=a0.w; l[4]=a1.x;l[5]=a1.y;l[6]=a1.z;l[7]=a1.w;
        l[8]=a2.x;l[9]=a2.y;l[10]=a2.z;l[11]=a2.w; l[12]=a3.x;l[13]=a3.y;l[14]=a3.z;l[15]=a3.w;
        l[16]=a4.x;l[17]=a4.y;l[18]=a4.z;l[19]=a4.w;
        if (jt == 1) {
#pragma unroll
          for (int k = 0; k < 16; ++k) sc[k] = l[k + 1];
        } else {
#pragma unroll
          for (int k = 0; k < 16; ++k) sc[k] = l[k + 3];
        }
      }
    }
    // colmax accumulate (x2 source: max over window rows = di axis)
#pragma unroll
    for (int k = 0; k < 16; ++k) colmax[k] = fmaxf(colmax[k], sc[k]);
    // rowmax (x3): sliding max over dj, write bf16 transposed: [n][r*256+c]
#pragma unroll
    for (int n = 0; n < 14; ++n)
      rowmaxT[n * 776 + r * 256 + c] = f2b(fmaxf(fmaxf(sc[n], sc[n + 1]), sc[n + 2]));
    // x1 stage: 32-channel group max per staged col via shfl butterfly
#pragma unroll
    for (int col = 0; col < 16; ++col) {
      float m = sc[col];
      m = fmaxf(m, __shfl_xor(m, 1));
      m = fmaxf(m, __shfl_xor(m, 2));
      m = fmaxf(m, __shfl_xor(m, 4));
      m = fmaxf(m, __shfl_xor(m, 8));
      m = fmaxf(m, __shfl_xor(m, 16));
      if (gc == col) gmax_s[g * 48 + r * 16 + col] = m;
    }
    // pack window row to bf16 pairs (kept in regs for final aggregation)
#pragma unroll
    for (int k = 0; k < 8; ++k)
      win_p[r][k] = (u32)f2b(sc[2 * k]) | ((u32)f2b(sc[2 * k + 1]) << 16);
  }
  // colmaxT write: [col][c]
#pragma unroll
  for (int col = 0; col < 16; ++col)
    colmaxT[col * 264 + c] = f2b(colmax[col]);
  // x1T scatter (reads own-wave gmax_s writes; drain LDS queue first)
  asm volatile("s_waitcnt lgkmcnt(0)" ::: "memory");
#pragma unroll
  for (int rep = 0; rep < 4; ++rep) {
    int idx = gc + 32 * rep;
    if (idx < 126) {
      int n = idx / 9, r9 = idx - n * 9, ki = r9 / 3, kj = r9 - ki * 3;
      x1T[n * 104 + g * 9 + r9] = f2b(gmax_s[g * 48 + ki * 16 + n + kj]);
    }
  }
  __syncthreads();

  // ---------------- P2: conv1 MFMA, waves split K (13/13/13/12 ks) ----------------
  v4f acc[5];
#pragma unroll
  for (int mt = 0; mt < 5; ++mt) acc[mt] = (v4f){0.f, 0.f, 0.f, 0.f};
  const int ks0 = w * 13, ks1 = (w == 3) ? 51 : ks0 + 13;

  auto loadB = [&](int ks) -> v8s {
    if (ks < 24) {
      int kj = ks >> 3, c0 = (ks & 7) * 32;
      return *(v8s*)&colmaxT[(ml + kj) * 264 + c0 + quad * 8];
    } else if (ks < 48) {
      return *(v8s*)&rowmaxT[ml * 776 + (ks - 24) * 32 + quad * 8];
    } else {
      return *(v8s*)&x1T[ml * 104 + (ks - 48) * 32 + quad * 8];
    }
  };

  {
    v8s bf_c = loadB(ks0);
    v8s af_c[5];
    {
      const int k0 = ks0 * 32 + quad * 8;
#pragma unroll
      for (int mt = 0; mt < 5; ++mt)
        af_c[mt] = *(const v8s*)&w1bf[(mt * 16 + ml) * KP1 + k0];
    }
    for (int ks = ks0; ks < ks1; ++ks) {
      v8s bf_n, af_n[5];
      if (ks + 1 < ks1) {
        bf_n = loadB(ks + 1);
        const int k0n = (ks + 1) * 32 + quad * 8;
#pragma unroll
        for (int mt = 0; mt < 5; ++mt)
          af_n[mt] = *(const v8s*)&w1bf[(mt * 16 + ml) * KP1 + k0n];
      }
#pragma unroll
      for (int mt = 0; mt < 5; ++mt)
        acc[mt] = __builtin_amdgcn_mfma_f32_16x16x32_bf16(af_c[mt], bf_c, acc[mt], 0, 0, 0);
      if (ks + 1 < ks1) {
        bf_c = bf_n;
#pragma unroll
        for (int mt = 0; mt < 5; ++mt) af_c[mt] = af_n[mt];
      }
    }
  }
  __syncthreads();                // all LDS reads of colmaxT/rowmaxT/x1T complete

  // ---------------- P3: partials to LDS (aliases rowmaxT) ----------------
#pragma unroll
  for (int mt = 0; mt < 5; ++mt)
    *(v4f*)&partA[((w * 5 + mt) * 16 + ml) * 16 + quad * 4] = acc[mt];
  __syncthreads();

  // ---------------- P4: reduce partials -> y1b bf16 [n][104] (aliases x1T) ----------------
  u16* y1b = x1T;
#pragma unroll
  for (int it = 0; it < 4; ++it) {
    int e = t + it * 256;
    if (e < NO1 * PPB) {
      int m = e / PPB, n = e - m * PPB;
      float s = b1[m];
#pragma unroll
      for (int ww = 0; ww < 4; ++ww)
        s += partA[((ww * 5 + (m >> 4)) * 16 + n) * 16 + (m & 15)];
      y1b[n * 104 + m] = f2b(s);   // pads [72,96) & rows 14,15 stay zero from x1T
    }
  }
  __syncthreads();

  // ---------------- P5: conv2 MFMA -> y2L [n][296] f32 (aliases partials) ----------------
  {
    v8s bfr[3];
#pragma unroll
    for (int ks = 0; ks < 3; ++ks)
      bfr[ks] = *(v8s*)&y1b[ml * 104 + ks * 32 + quad * 8];
    const int mt0 = (w < 2) ? 5 * w : 10 + 4 * (w - 2);
    const int mtn = (w < 2) ? 5 : 4;
    for (int mi = 0; mi < mtn; ++mi) {
      const int mt = mt0 + mi;
      v4f a2 = (v4f){0.f, 0.f, 0.f, 0.f};
#pragma unroll
      for (int ks = 0; ks < 3; ++ks) {
        v8s af = *(const v8s*)&w2bf[(mt * 16 + ml) * 96 + ks * 32 + quad * 8];
        a2 = __builtin_amdgcn_mfma_f32_16x16x32_bf16(af, bfr[ks], a2, 0, 0, 0);
      }
      const int o0 = mt * 16 + quad * 4;
      const float4 bv = *(const float4*)(b2 + o0);
      a2[0] += bv.x; a2[1] += bv.y; a2[2] += bv.z; a2[3] += bv.w;
      *(v4f*)&y2L[ml * 296 + o0] = a2;
    }
  }
  __syncthreads();

  // ---------------- P6: softmax over k(9), 448 (g,nn,n) slots, in place ----------------
#pragma unroll
  for (int it = 0; it < 2; ++it) {
    int s2 = t + it * 256;
    if (s2 < 448) {
      int gg = s2 / 56, rem = s2 - gg * 56, nn = rem / PPB, n = rem - nn * PPB;
      float* bp = &y2L[n * 296 + gg * 36 + nn];
      float v9[9], m = -1e30f;
#pragma unroll
      for (int k = 0; k < 9; ++k) { v9[k] = bp[k * 4]; m = fmaxf(m, v9[k]); }
      float sum = 0.f;
#pragma unroll
      for (int k = 0; k < 9; ++k) { v9[k] = __expf(v9[k] - m); sum += v9[k]; }
      float inv = 1.f / sum;
#pragma unroll
      for (int k = 0; k < 9; ++k) bp[k * 4] = v9[k] * inv;
    }
  }
  __syncthreads();

  // ---------------- P7: aggregation from register window ----------------
  float a0s[14], a1s[14], a2s[14], a3s[14];
#pragma unroll
  for (int n = 0; n < 14; ++n) {
    const v4f* wp = (const v4f*)&y2L[n * 296 + g * 36];   // 9 x float4 (k-major, nn inside)
    float a0 = 0.f, a1 = 0.f, a2v = 0.f, a3 = 0.f;
#pragma unroll
    for (int r = 0; r < 3; ++r) {
      float x0, x1, x2v;
      if ((n & 1) == 0) {
        u32 ua = win_p[r][n >> 1], ub = win_p[r][(n >> 1) + 1];
        x0  = __uint_as_float(ua << 16);
        x1  = __uint_as_float(ua & 0xffff0000u);
        x2v = __uint_as_float(ub << 16);
      } else {
        u32 ua = win_p[r][n >> 1], ub = win_p[r][(n >> 1) + 1];
        x0  = __uint_as_float(ua & 0xffff0000u);
        x1  = __uint_as_float(ub << 16);
        x2v = __uint_as_float(ub & 0xffff0000u);
      }
#pragma unroll
      for (int kj = 0; kj < 3; ++kj) {
        v4f wv = wp[r * 3 + kj];
        float x = (kj == 0) ? x0 : (kj == 1) ? x1 : x2v;
        a0  = fmaf(x, wv[0], a0);
        a1  = fmaf(x, wv[1], a1);
        a2v = fmaf(x, wv[2], a2v);
        a3  = fmaf(x, wv[3], a3);
      }
    }
    a0s[n] = a0; a1s[n] = a1; a2s[n] = a2v; a3s[n] = a3;
  }

  // ---------------- P8: 4-chunk LDS transpose + coalesced stores ----------------
  const int cl = c & 63;
  for (int ch = 0; ch < 4; ++ch) {
    if ((c >> 6) == ch) {
#pragma unroll
      for (int n = 0; n < 14; ++n) {
        float2 lo2; lo2.x = a0s[n]; lo2.y = a1s[n];
        float2 hi2; hi2.x = a2s[n]; hi2.y = a3s[n];
        *(float2*)&tile[cl * 60 + 2 * n] = lo2;          // di=0 row
        *(float2*)&tile[cl * 60 + 28 + 2 * n] = hi2;     // di=1 row
      }
    }
    __syncthreads();
#pragma unroll
    for (int it = 0; it < 4; ++it) {
      int f = t + it * 256;
      if (f < 896) {
        int rr = f / 7, xi = f - rr * 7;
        int cg = ch * 64 + (rr >> 1), di = rr & 1;
        v4f val = *(v4f*)&tile[(rr >> 1) * 60 + di * 28 + xi * 4];
        *(v4f*)&out[((size_t)(b * CC + cg) * H2 + (size_t)(2 * i + di)) * W2D
                    + 28 * jt + xi * 4] = val;
      }
    }
    __syncthreads();
  }
}

extern "C" void kernel_launch(void* const* d_in, const int* in_sizes, int n_in,
                              void* d_out, int out_size, void* d_ws, size_t ws_size,
                              hipStream_t stream) {
  const float* in = (const float*)d_in[0];
  const float* W1 = (const float*)d_in[1];
  const float* b1 = (const float*)d_in[2];
  const float* W2 = (const float*)d_in[3];
  const float* b2 = (const float*)d_in[4];
  float* out = (float*)d_out;

  u16* w1bf = (u16*)d_ws;
  u16* w2bf = (u16*)((char*)d_ws + W2BF_OFF_B);

  const int B = in_sizes[0] / (CC * HH * WWID);

  kConvW<<<dim3((W1BF_ELEMS + NO2 * 96 + 255) / 256), 256, 0, stream>>>(W1, W2, w1bf, w2bf);
  dim3 grid(WWID / PPB, HH, B);
  kFused<<<grid, 256, 0, stream>>>(in, w1bf, b1, w2bf, b2, out);
}